// Round 2
// baseline (671.790 us; speedup 1.0000x reference)
//
#include <hip/hip_runtime.h>

#define N_NODES 50000
#define N_EDGES 800000

static inline size_t align256(size_t x) { return (x + 255) & ~(size_t)255; }

// ---------------- CSR build ----------------

__global__ void count_kernel(const int* __restrict__ dst, int* __restrict__ counts, int E) {
    int e = blockIdx.x * blockDim.x + threadIdx.x;
    if (e < E) atomicAdd(&counts[dst[e]], 1);
}

__global__ void scan_kernel(const int* __restrict__ counts, int* __restrict__ row_ptr, int n) {
    __shared__ int sd[1024];
    __shared__ int carry_s;
    if (threadIdx.x == 0) { carry_s = 0; row_ptr[0] = 0; }
    __syncthreads();
    for (int base = 0; base < n; base += 1024) {
        int i = base + (int)threadIdx.x;
        int v = (i < n) ? counts[i] : 0;
        sd[threadIdx.x] = v;
        __syncthreads();
        #pragma unroll
        for (int off = 1; off < 1024; off <<= 1) {
            int t = 0;
            if ((int)threadIdx.x >= off) t = sd[threadIdx.x - off];
            __syncthreads();
            sd[threadIdx.x] += t;
            __syncthreads();
        }
        if (i < n) row_ptr[i + 1] = carry_s + sd[threadIdx.x];
        __syncthreads();
        if (threadIdx.x == 1023) carry_s += sd[1023];
        __syncthreads();
    }
}

__global__ void prep_kernel(const int* __restrict__ row_ptr, const int* __restrict__ counts,
                            int* __restrict__ cursor, float* __restrict__ dis, int N) {
    int v = blockIdx.x * blockDim.x + threadIdx.x;
    if (v < N) {
        cursor[v] = row_ptr[v];
        dis[v] = rsqrtf((float)(counts[v] + 1));   // deg includes self-loop, >= 1
    }
}

__global__ void fill_kernel(const int* __restrict__ src, const int* __restrict__ dst,
                            int* __restrict__ cursor, int* __restrict__ col, int E) {
    int e = blockIdx.x * blockDim.x + threadIdx.x;
    if (e < E) {
        int p = atomicAdd(&cursor[dst[e]], 1);
        col[p] = src[e];
    }
}

// ---------------- GEMM with fused dis-row-scale: G = diag(dis) * (A @ W) ----------------
// A: [M,K] row-major, W: [K,N] row-major, G: [M,N]. N % 64 == 0, K % 16 == 0.

#define BM 64
#define BN 64
#define BK 16

__global__ __launch_bounds__(256) void gemm_scale(
    const float* __restrict__ A, const float* __restrict__ W,
    const float* __restrict__ dis, float* __restrict__ G,
    int M, int N, int K) {
    __shared__ float As[BK][BM + 1];
    __shared__ float Bs[BK][BN];

    int t  = threadIdx.x;
    int tx = t & 15, ty = t >> 4;
    int m0 = blockIdx.y * BM;
    int n0 = blockIdx.x * BN;

    int arow = t >> 2;          // 0..63 : row within A tile
    int akq  = (t & 3) * 4;     // 0,4,8,12 : k quad
    int brow = t >> 4;          // 0..15 : k within B tile
    int bcol = (t & 15) * 4;    // 0..60 : col quad

    float acc[4][4] = {};

    for (int kt = 0; kt < K; kt += BK) {
        float4 av = make_float4(0.f, 0.f, 0.f, 0.f);
        if (m0 + arow < M)
            av = *(const float4*)(A + (long)(m0 + arow) * K + kt + akq);
        As[akq + 0][arow] = av.x;
        As[akq + 1][arow] = av.y;
        As[akq + 2][arow] = av.z;
        As[akq + 3][arow] = av.w;

        float4 bv = *(const float4*)(W + (long)(kt + brow) * N + n0 + bcol);
        *(float4*)&Bs[brow][bcol] = bv;

        __syncthreads();
        #pragma unroll
        for (int k = 0; k < BK; ++k) {
            float a[4], b[4];
            #pragma unroll
            for (int i = 0; i < 4; ++i) a[i] = As[k][ty * 4 + i];
            #pragma unroll
            for (int j = 0; j < 4; ++j) b[j] = Bs[k][tx * 4 + j];
            #pragma unroll
            for (int i = 0; i < 4; ++i)
                #pragma unroll
                for (int j = 0; j < 4; ++j)
                    acc[i][j] += a[i] * b[j];
        }
        __syncthreads();
    }

    #pragma unroll
    for (int i = 0; i < 4; ++i) {
        int m = m0 + ty * 4 + i;
        if (m < M) {
            float s = dis[m];
            float4 o = make_float4(acc[i][0] * s, acc[i][1] * s, acc[i][2] * s, acc[i][3] * s);
            *(float4*)(G + (long)m * N + n0 + tx * 4) = o;
        }
    }
}

// ---------------- Aggregation: out[v] = act(dis[v]*(sum_{u->v} g[u] + g[v]) + b) ----------------
// One block per node, blockDim.x == D (64/128/256).

template <bool RELU>
__global__ void agg_kernel(const float* __restrict__ g, const int* __restrict__ row_ptr,
                           const int* __restrict__ col, const float* __restrict__ dis,
                           const float* __restrict__ bias, float* __restrict__ out,
                           int D) {
    int v = blockIdx.x;
    int j = threadIdx.x;
    int s = row_ptr[v], e = row_ptr[v + 1];

    float sum = g[(long)v * D + j];     // self-loop term
    int i = s;
    for (; i + 4 <= e; i += 4) {
        int u0 = col[i], u1 = col[i + 1], u2 = col[i + 2], u3 = col[i + 3];
        float f0 = g[(long)u0 * D + j];
        float f1 = g[(long)u1 * D + j];
        float f2 = g[(long)u2 * D + j];
        float f3 = g[(long)u3 * D + j];
        sum += (f0 + f1) + (f2 + f3);
    }
    for (; i < e; ++i)
        sum += g[(long)col[i] * D + j];

    float r = dis[v] * sum + bias[j];
    if (RELU) r = fmaxf(r, 0.f);
    out[(long)v * D + j] = r;
}

// ---------------- launch ----------------

extern "C" void kernel_launch(void* const* d_in, const int* in_sizes, int n_in,
                              void* d_out, int out_size, void* d_ws, size_t ws_size,
                              hipStream_t stream) {
    const int N = N_NODES, E = N_EDGES;

    const float* x   = (const float*)d_in[0];
    const int*   ei  = (const int*)d_in[1];
    const int*   src = ei;
    const int*   dst = ei + E;
    const float* W1 = (const float*)d_in[2];  const float* b1 = (const float*)d_in[3];
    const float* W2 = (const float*)d_in[4];  const float* b2 = (const float*)d_in[5];
    const float* W3 = (const float*)d_in[6];  const float* b3 = (const float*)d_in[7];
    const float* W4 = (const float*)d_in[8];  const float* b4 = (const float*)d_in[9];
    float* out = (float*)d_out;

    // workspace carve-up
    char* w = (char*)d_ws;
    int*   counts  = (int*)w;    w += align256((size_t)N * 4);
    int*   row_ptr = (int*)w;    w += align256((size_t)(N + 1) * 4);
    int*   cursor  = (int*)w;    w += align256((size_t)N * 4);
    float* dis     = (float*)w;  w += align256((size_t)N * 4);
    int*   col     = (int*)w;    w += align256((size_t)E * 4);
    float* B1      = (float*)w;  w += align256((size_t)N * 256 * 4);  // g buffer
    float* B2      = (float*)w;  w += align256((size_t)N * 256 * 4);  // feat buffer (<=256)
    float* B3      = (float*)w;  w += align256((size_t)N * 64 * 4);   // feat buffer (64)

    // ---- CSR build (once per call; reused by all 4 layers) ----
    hipMemsetAsync(counts, 0, (size_t)N * 4, stream);
    count_kernel<<<(E + 255) / 256, 256, 0, stream>>>(dst, counts, E);
    scan_kernel<<<1, 1024, 0, stream>>>(counts, row_ptr, N);
    prep_kernel<<<(N + 255) / 256, 256, 0, stream>>>(row_ptr, counts, cursor, dis, N);
    fill_kernel<<<(E + 255) / 256, 256, 0, stream>>>(src, dst, cursor, col, E);

    const int gy = (N + BM - 1) / BM;   // 782

    // ---- layer 1: x[,128] @ W1[128,256] -> B2[,256], relu ----
    gemm_scale<<<dim3(256 / BN, gy), 256, 0, stream>>>(x, W1, dis, B1, N, 256, 128);
    agg_kernel<true><<<N, 256, 0, stream>>>(B1, row_ptr, col, dis, b1, B2, 256);

    // ---- layer 2: B2[,256] @ W2[256,64] -> B3[,64], relu ----
    gemm_scale<<<dim3(64 / BN, gy), 256, 0, stream>>>(B2, W2, dis, B1, N, 64, 256);
    agg_kernel<true><<<N, 64, 0, stream>>>(B1, row_ptr, col, dis, b2, B3, 64);

    // ---- layer 3: B3[,64] @ W3[64,256] -> B2[,256], relu ----
    gemm_scale<<<dim3(256 / BN, gy), 256, 0, stream>>>(B3, W3, dis, B1, N, 256, 64);
    agg_kernel<true><<<N, 256, 0, stream>>>(B1, row_ptr, col, dis, b3, B2, 256);

    // ---- layer 4: B2[,256] @ W4[256,128] -> d_out[,128], no relu ----
    gemm_scale<<<dim3(128 / BN, gy), 256, 0, stream>>>(B2, W4, dis, B1, N, 128, 256);
    agg_kernel<false><<<N, 128, 0, stream>>>(B1, row_ptr, col, dis, b4, out, 128);
}

// Round 3
// 452.389 us; speedup vs baseline: 1.4850x; 1.4850x over previous
//
#include <hip/hip_runtime.h>

#define N_NODES 50000
#define N_EDGES 800000

static inline size_t align256(size_t x) { return (x + 255) & ~(size_t)255; }

// ---------------- CSR build ----------------

__global__ void count_kernel(const int* __restrict__ dst, int* __restrict__ counts, int E) {
    int e = blockIdx.x * blockDim.x + threadIdx.x;
    if (e < E) atomicAdd(&counts[dst[e]], 1);
}

// 3-kernel scan: per-block inclusive scan -> serial scan of block sums -> add offsets
__global__ void scan1_kernel(const int* __restrict__ counts, int* __restrict__ row_ptr,
                             int* __restrict__ bsum, int n) {
    __shared__ int sd[1024];
    int i = blockIdx.x * 1024 + threadIdx.x;
    int v = (i < n) ? counts[i] : 0;
    sd[threadIdx.x] = v;
    __syncthreads();
    #pragma unroll
    for (int off = 1; off < 1024; off <<= 1) {
        int t = 0;
        if ((int)threadIdx.x >= off) t = sd[threadIdx.x - off];
        __syncthreads();
        sd[threadIdx.x] += t;
        __syncthreads();
    }
    if (i < n) row_ptr[i + 1] = sd[threadIdx.x];   // chunk-local inclusive
    if (threadIdx.x == 1023) bsum[blockIdx.x] = sd[1023];
}

__global__ void scan2_kernel(int* __restrict__ bsum, int nb) {
    if (threadIdx.x == 0) {
        int acc = 0;
        for (int b = 0; b < nb; ++b) { int t = bsum[b]; bsum[b] = acc; acc += t; }
    }
}

__global__ void scan3_kernel(int* __restrict__ row_ptr, const int* __restrict__ bsum, int n) {
    int i = blockIdx.x * blockDim.x + threadIdx.x;
    if (i == 0) row_ptr[0] = 0;
    if (i < n) row_ptr[i + 1] += bsum[i >> 10];
}

__global__ void prep_kernel(const int* __restrict__ row_ptr, const int* __restrict__ counts,
                            int* __restrict__ cursor, float* __restrict__ dis, int N) {
    int v = blockIdx.x * blockDim.x + threadIdx.x;
    if (v < N) {
        cursor[v] = row_ptr[v];
        dis[v] = rsqrtf((float)(counts[v] + 1));   // deg includes self-loop
    }
}

__global__ void fill_kernel(const int* __restrict__ src, const int* __restrict__ dst,
                            int* __restrict__ cursor, int* __restrict__ col, int E) {
    int e = blockIdx.x * blockDim.x + threadIdx.x;
    if (e < E) {
        int p = atomicAdd(&cursor[dst[e]], 1);
        col[p] = src[e];
    }
}

// xs[v,:] = dis[v] * x[v,:]   (D = 128, vectorized float4)
__global__ void scale_kernel(const float* __restrict__ x, const float* __restrict__ dis,
                             float* __restrict__ xs, int nquads) {
    int q = blockIdx.x * blockDim.x + threadIdx.x;
    if (q < nquads) {
        int v = q >> 5;                 // 128/4 = 32 quads per row
        float s = dis[v];
        float4 t = *(const float4*)(x + (size_t)q * 4);
        t.x *= s; t.y *= s; t.z *= s; t.w *= s;
        *(float4*)(xs + (size_t)q * 4) = t;
    }
}

// ---------------- GEMM: G = epi(A @ W), A:[M,K], W:[K,N] row-major ----------------
// EPI 0: G[m,:] = dis[m] * acc          (feeds agg-after)
// EPI 1: G[m,:] = relu(acc + bias)      (agg-first layers, full GCN layer output)

#define GBM 128
#define GBN 64
#define GBK 16

template <int EPI>
__global__ __launch_bounds__(256) void gemm_k(
    const float* __restrict__ A, const float* __restrict__ W,
    const float* __restrict__ dis, const float* __restrict__ bias,
    float* __restrict__ G, int M, int N, int K) {
    __shared__ float As[GBK][GBM + 4];
    __shared__ float Bs[GBK][GBN + 4];

    int t  = threadIdx.x;
    int tx = t & 15, ty = t >> 4;
    int m0 = blockIdx.y * GBM;
    int n0 = blockIdx.x * GBN;

    int arow = t >> 1;           // 0..127
    int akq  = (t & 1) * 8;      // 0 or 8
    int brow = t >> 4;           // 0..15
    int bcol = (t & 15) * 4;     // 0..60

    bool arow_ok = (m0 + arow) < M;
    const float* Arow = A + (long)(m0 + arow) * K + akq;

    float acc[8][4] = {};

    for (int kt = 0; kt < K; kt += GBK) {
        float4 a0 = make_float4(0.f, 0.f, 0.f, 0.f), a1 = a0;
        if (arow_ok) {
            a0 = *(const float4*)(Arow + kt);
            a1 = *(const float4*)(Arow + kt + 4);
        }
        As[akq + 0][arow] = a0.x; As[akq + 1][arow] = a0.y;
        As[akq + 2][arow] = a0.z; As[akq + 3][arow] = a0.w;
        As[akq + 4][arow] = a1.x; As[akq + 5][arow] = a1.y;
        As[akq + 6][arow] = a1.z; As[akq + 7][arow] = a1.w;

        *(float4*)&Bs[brow][bcol] = *(const float4*)(W + (long)(kt + brow) * N + n0 + bcol);

        __syncthreads();
        #pragma unroll
        for (int k = 0; k < GBK; ++k) {
            float4 a0v = *(const float4*)&As[k][ty * 8];
            float4 a1v = *(const float4*)&As[k][ty * 8 + 4];
            float4 bv  = *(const float4*)&Bs[k][tx * 4];
            float av[8] = {a0v.x, a0v.y, a0v.z, a0v.w, a1v.x, a1v.y, a1v.z, a1v.w};
            float bb[4] = {bv.x, bv.y, bv.z, bv.w};
            #pragma unroll
            for (int i = 0; i < 8; ++i)
                #pragma unroll
                for (int j = 0; j < 4; ++j)
                    acc[i][j] += av[i] * bb[j];
        }
        __syncthreads();
    }

    float4 bv = make_float4(0.f, 0.f, 0.f, 0.f);
    if (EPI == 1) bv = *(const float4*)(bias + n0 + tx * 4);

    #pragma unroll
    for (int i = 0; i < 8; ++i) {
        int m = m0 + ty * 8 + i;
        if (m < M) {
            float4 o;
            if (EPI == 0) {
                float s = dis[m];
                o = make_float4(acc[i][0] * s, acc[i][1] * s, acc[i][2] * s, acc[i][3] * s);
            } else {
                o = make_float4(fmaxf(acc[i][0] + bv.x, 0.f), fmaxf(acc[i][1] + bv.y, 0.f),
                                fmaxf(acc[i][2] + bv.z, 0.f), fmaxf(acc[i][3] + bv.w, 0.f));
            }
            *(float4*)(G + (long)m * N + n0 + tx * 4) = o;
        }
    }
}

// ---------------- Aggregation ----------------
// sum = g[v,:] + sum_{u->v} g[u,:]   (one block per node, blockDim.x == D)
// MODE 0: out = dis[v]*sum                       (agg-first; g is dis-prescaled)
// MODE 1: out = relu(dis[v]*sum + b)             (agg-after, relu)
// MODE 2: out = dis[v]*relu(dis[v]*sum + b)      (agg-after, relu, prescale for next agg-first)
// MODE 3: out = dis[v]*sum + b                   (agg-after, final layer)

template <int MODE>
__global__ void agg_kernel(const float* __restrict__ g, const int* __restrict__ row_ptr,
                           const int* __restrict__ col, const float* __restrict__ dis,
                           const float* __restrict__ bias, float* __restrict__ out,
                           int D) {
    int v = blockIdx.x;
    int j = threadIdx.x;
    int s = row_ptr[v], e = row_ptr[v + 1];

    float sum = g[(long)v * D + j];     // self-loop term
    int i = s;
    for (; i + 4 <= e; i += 4) {
        int u0 = col[i], u1 = col[i + 1], u2 = col[i + 2], u3 = col[i + 3];
        float f0 = g[(long)u0 * D + j];
        float f1 = g[(long)u1 * D + j];
        float f2 = g[(long)u2 * D + j];
        float f3 = g[(long)u3 * D + j];
        sum += (f0 + f1) + (f2 + f3);
    }
    for (; i < e; ++i)
        sum += g[(long)col[i] * D + j];

    float dv = dis[v];
    float r;
    if (MODE == 0) {
        r = dv * sum;
    } else {
        r = dv * sum + bias[j];
        if (MODE == 1 || MODE == 2) r = fmaxf(r, 0.f);
        if (MODE == 2) r *= dv;
    }
    out[(long)v * D + j] = r;
}

// ---------------- launch ----------------

extern "C" void kernel_launch(void* const* d_in, const int* in_sizes, int n_in,
                              void* d_out, int out_size, void* d_ws, size_t ws_size,
                              hipStream_t stream) {
    const int N = N_NODES, E = N_EDGES;

    const float* x   = (const float*)d_in[0];
    const int*   ei  = (const int*)d_in[1];
    const int*   src = ei;
    const int*   dst = ei + E;
    const float* W1 = (const float*)d_in[2];  const float* b1 = (const float*)d_in[3];
    const float* W2 = (const float*)d_in[4];  const float* b2 = (const float*)d_in[5];
    const float* W3 = (const float*)d_in[6];  const float* b3 = (const float*)d_in[7];
    const float* W4 = (const float*)d_in[8];  const float* b4 = (const float*)d_in[9];
    float* out = (float*)d_out;

    // workspace carve-up
    char* w = (char*)d_ws;
    int*   counts  = (int*)w;    w += align256((size_t)N * 4);
    int*   row_ptr = (int*)w;    w += align256((size_t)(N + 1) * 4);
    int*   cursor  = (int*)w;    w += align256((size_t)N * 4);
    float* dis     = (float*)w;  w += align256((size_t)N * 4);
    int*   bsum    = (int*)w;    w += align256((size_t)64 * 4);
    int*   col     = (int*)w;    w += align256((size_t)E * 4);
    float* BA      = (float*)w;  w += align256((size_t)N * 256 * 4);  // h1 / h3
    float* BB      = (float*)w;  w += align256((size_t)N * 128 * 4);  // xs / g4
    float* BC      = (float*)w;  w += align256((size_t)N * 128 * 4);  // t1
    float* BD      = (float*)w;  w += align256((size_t)N * 64 * 4);   // g2 / t3
    float* BE      = (float*)w;  w += align256((size_t)N * 64 * 4);   // h2s

    // ---- CSR build (once per call; reused by all 4 layers) ----
    const int nb = (N + 1023) / 1024;   // 49
    hipMemsetAsync(counts, 0, (size_t)N * 4, stream);
    count_kernel<<<(E + 255) / 256, 256, 0, stream>>>(dst, counts, E);
    scan1_kernel<<<nb, 1024, 0, stream>>>(counts, row_ptr, bsum, N);
    scan2_kernel<<<1, 64, 0, stream>>>(bsum, nb);
    scan3_kernel<<<(N + 255) / 256, 256, 0, stream>>>(row_ptr, bsum, N);
    prep_kernel<<<(N + 255) / 256, 256, 0, stream>>>(row_ptr, counts, cursor, dis, N);
    fill_kernel<<<(E + 255) / 256, 256, 0, stream>>>(src, dst, cursor, col, E);

    const int gy = (N + GBM - 1) / GBM;   // 391

    // ---- layer 1 (agg-first): t1 = Âs xs ; h1 = relu(t1 @ W1 + b1) ----
    scale_kernel<<<(N * 32 + 255) / 256, 256, 0, stream>>>(x, dis, BB, N * 32);
    agg_kernel<0><<<N, 128, 0, stream>>>(BB, row_ptr, col, dis, b1, BC, 128);
    gemm_k<1><<<dim3(256 / GBN, gy), 256, 0, stream>>>(BC, W1, dis, b1, BA, N, 256, 128);

    // ---- layer 2 (agg-after): g2 = dis*(h1 @ W2) ; h2s = dis*relu(agg + b2) ----
    gemm_k<0><<<dim3(64 / GBN, gy), 256, 0, stream>>>(BA, W2, dis, b2, BD, N, 64, 256);
    agg_kernel<2><<<N, 64, 0, stream>>>(BD, row_ptr, col, dis, b2, BE, 64);

    // ---- layer 3 (agg-first): t3 = Âs h2s ; h3 = relu(t3 @ W3 + b3) ----
    agg_kernel<0><<<N, 64, 0, stream>>>(BE, row_ptr, col, dis, b3, BD, 64);
    gemm_k<1><<<dim3(256 / GBN, gy), 256, 0, stream>>>(BD, W3, dis, b3, BA, N, 256, 64);

    // ---- layer 4 (agg-after): g4 = dis*(h3 @ W4) ; out = agg + b4 ----
    gemm_k<0><<<dim3(128 / GBN, gy), 256, 0, stream>>>(BA, W4, dis, b4, BB, N, 128, 256);
    agg_kernel<3><<<N, 128, 0, stream>>>(BB, row_ptr, col, dis, b4, out, 128);
}

// Round 4
// 415.847 us; speedup vs baseline: 1.6155x; 1.0879x over previous
//
#include <hip/hip_runtime.h>

#define N_NODES 50000
#define N_EDGES 800000

static inline size_t align256(size_t x) { return (x + 255) & ~(size_t)255; }

typedef short bf16x8 __attribute__((ext_vector_type(8)));   // 8 bf16 in 4 VGPRs
typedef float f32x4 __attribute__((ext_vector_type(4)));

__device__ __forceinline__ unsigned short f2bf_rne(float v) {
    unsigned u = __builtin_bit_cast(unsigned, v);
    u += 0x7fffu + ((u >> 16) & 1u);
    return (unsigned short)(u >> 16);
}
__device__ __forceinline__ float bf2f(unsigned short h) {
    unsigned u = (unsigned)h << 16;
    return __builtin_bit_cast(float, u);
}

// ---------------- CSR build ----------------

__global__ void count_kernel(const int* __restrict__ dst, int* __restrict__ counts, int E) {
    int e = blockIdx.x * blockDim.x + threadIdx.x;
    if (e < E) atomicAdd(&counts[dst[e]], 1);
}

__global__ void scan1_kernel(const int* __restrict__ counts, int* __restrict__ row_ptr,
                             int* __restrict__ bsum, int n) {
    __shared__ int sd[1024];
    int i = blockIdx.x * 1024 + threadIdx.x;
    int v = (i < n) ? counts[i] : 0;
    sd[threadIdx.x] = v;
    __syncthreads();
    #pragma unroll
    for (int off = 1; off < 1024; off <<= 1) {
        int t = 0;
        if ((int)threadIdx.x >= off) t = sd[threadIdx.x - off];
        __syncthreads();
        sd[threadIdx.x] += t;
        __syncthreads();
    }
    if (i < n) row_ptr[i + 1] = sd[threadIdx.x];
    if (threadIdx.x == 1023) bsum[blockIdx.x] = sd[1023];
}

__global__ void scan2_kernel(int* __restrict__ bsum, int nb) {
    if (threadIdx.x == 0) {
        int acc = 0;
        for (int b = 0; b < nb; ++b) { int t = bsum[b]; bsum[b] = acc; acc += t; }
    }
}

__global__ void scan3_kernel(int* __restrict__ row_ptr, const int* __restrict__ bsum, int n) {
    int i = blockIdx.x * blockDim.x + threadIdx.x;
    if (i == 0) row_ptr[0] = 0;
    if (i < n) row_ptr[i + 1] += bsum[i >> 10];
}

__global__ void prep_kernel(const int* __restrict__ row_ptr, const int* __restrict__ counts,
                            int* __restrict__ cursor, float* __restrict__ dis, int N) {
    int v = blockIdx.x * blockDim.x + threadIdx.x;
    if (v < N) {
        cursor[v] = row_ptr[v];
        dis[v] = rsqrtf((float)(counts[v] + 1));
    }
}

__global__ void fill_kernel(const int* __restrict__ src, const int* __restrict__ dst,
                            int* __restrict__ cursor, int* __restrict__ col, int E) {
    int e = blockIdx.x * blockDim.x + threadIdx.x;
    if (e < E) {
        int p = atomicAdd(&cursor[dst[e]], 1);
        col[p] = src[e];
    }
}

// xs[v,:] = dis[v] * x[v,:]   (D = 128)
__global__ void scale_kernel(const float* __restrict__ x, const float* __restrict__ dis,
                             float* __restrict__ xs, int nquads) {
    int q = blockIdx.x * blockDim.x + threadIdx.x;
    if (q < nquads) {
        int v = q >> 5;
        float s = dis[v];
        float4 t = *(const float4*)(x + (size_t)q * 4);
        t.x *= s; t.y *= s; t.z *= s; t.w *= s;
        *(float4*)(xs + (size_t)q * 4) = t;
    }
}

// ---------------- W packing: fragment-order hi/lo bf16 ----------------
// frag f = (k/32)*(N/16) + n/16 ; lane l elem j = W[k0 + (l>>4)*8 + j][nf*16 + (l&15)]

__global__ void pack_w(const float* __restrict__ W, unsigned short* __restrict__ Ph,
                       unsigned short* __restrict__ Pl, int K, int N) {
    int id = blockIdx.x * blockDim.x + threadIdx.x;
    int total = (K >> 5) * (N >> 4) * 64;
    if (id >= total) return;
    int l = id & 63;
    int f = id >> 6;
    int nf16 = N >> 4;
    int ks = f / nf16, nf = f - ks * nf16;
    int k0 = ks * 32 + (l >> 4) * 8;
    int n  = nf * 16 + (l & 15);
    #pragma unroll
    for (int j = 0; j < 8; ++j) {
        float v = W[(size_t)(k0 + j) * N + n];
        unsigned short hi = f2bf_rne(v);
        Ph[(size_t)id * 8 + j] = hi;
        Pl[(size_t)id * 8 + j] = f2bf_rne(v - bf2f(hi));
    }
}

// ---------------- MFMA GEMM (bf16x3 split): G = epi(A @ W) ----------------
// A as hi/lo bf16 [M,K] row-major; W pre-packed hi/lo fragments.
// EPI 0: Gf[m,:] = dis[m]*acc            (fp32, feeds agg-after)
// EPI 1: Oh/Ol   = split(relu(acc+bias)) (hi/lo bf16, feeds next GEMM)
// Tile 128x64, 256 threads = 4 waves, wave = 32x64. M % 16 == 0.

template <int EPI>
__global__ __launch_bounds__(256) void mfma_gemm(
    const unsigned short* __restrict__ Ah, const unsigned short* __restrict__ Al,
    const unsigned short* __restrict__ Bh, const unsigned short* __restrict__ Bl,
    const float* __restrict__ dis, const float* __restrict__ bias,
    float* __restrict__ Gf, unsigned short* __restrict__ Oh, unsigned short* __restrict__ Ol,
    int M, int N, int K) {

    int t = threadIdx.x;
    int w = t >> 6, l = t & 63;
    int m0 = blockIdx.y * 128 + w * 32;
    int n0 = blockIdx.x * 64;

    int lrow = l & 15;
    int lk   = (l >> 4) * 8;

    int r0 = m0 + lrow, r1 = m0 + 16 + lrow;
    bool ok0 = r0 < M, ok1 = r1 < M;          // uniform per frag (M%16==0)

    const unsigned short* pAh0 = Ah + (size_t)r0 * K + lk;
    const unsigned short* pAl0 = Al + (size_t)r0 * K + lk;
    const unsigned short* pAh1 = Ah + (size_t)r1 * K + lk;
    const unsigned short* pAl1 = Al + (size_t)r1 * K + lk;

    int nf16 = N >> 4;
    const unsigned short* pBh = Bh + (size_t)(n0 >> 4) * 512 + (size_t)l * 8;
    const unsigned short* pBl = Bl + (size_t)(n0 >> 4) * 512 + (size_t)l * 8;

    f32x4 acc[2][4] = {};
    bf16x8 z8 = {0, 0, 0, 0, 0, 0, 0, 0};

    #pragma unroll 2
    for (int kt = 0; kt < K; kt += 32) {
        bf16x8 ah0 = ok0 ? *(const bf16x8*)(pAh0 + kt) : z8;
        bf16x8 al0 = ok0 ? *(const bf16x8*)(pAl0 + kt) : z8;
        bf16x8 ah1 = ok1 ? *(const bf16x8*)(pAh1 + kt) : z8;
        bf16x8 al1 = ok1 ? *(const bf16x8*)(pAl1 + kt) : z8;

        size_t boff = (size_t)(kt >> 5) * nf16 * 512;
        #pragma unroll
        for (int c = 0; c < 4; ++c) {
            bf16x8 bh = *(const bf16x8*)(pBh + boff + (size_t)c * 512);
            bf16x8 bl = *(const bf16x8*)(pBl + boff + (size_t)c * 512);
            acc[0][c] = __builtin_amdgcn_mfma_f32_16x16x32_bf16(ah0, bh, acc[0][c], 0, 0, 0);
            acc[0][c] = __builtin_amdgcn_mfma_f32_16x16x32_bf16(al0, bh, acc[0][c], 0, 0, 0);
            acc[0][c] = __builtin_amdgcn_mfma_f32_16x16x32_bf16(ah0, bl, acc[0][c], 0, 0, 0);
            acc[1][c] = __builtin_amdgcn_mfma_f32_16x16x32_bf16(ah1, bh, acc[1][c], 0, 0, 0);
            acc[1][c] = __builtin_amdgcn_mfma_f32_16x16x32_bf16(al1, bh, acc[1][c], 0, 0, 0);
            acc[1][c] = __builtin_amdgcn_mfma_f32_16x16x32_bf16(ah1, bl, acc[1][c], 0, 0, 0);
        }
    }

    float bvals[4];
    if (EPI == 1) {
        #pragma unroll
        for (int c = 0; c < 4; ++c) bvals[c] = bias[n0 + c * 16 + lrow];
    }

    #pragma unroll
    for (int rf = 0; rf < 2; ++rf) {
        int mb = m0 + rf * 16 + (l >> 4) * 4;
        #pragma unroll
        for (int r = 0; r < 4; ++r) {
            int m = mb + r;
            if (m < M) {
                if (EPI == 0) {
                    float s = dis[m];
                    #pragma unroll
                    for (int c = 0; c < 4; ++c) {
                        int n = n0 + c * 16 + lrow;
                        Gf[(size_t)m * N + n] = s * acc[rf][c][r];
                    }
                } else {
                    #pragma unroll
                    for (int c = 0; c < 4; ++c) {
                        int n = n0 + c * 16 + lrow;
                        float v = fmaxf(acc[rf][c][r] + bvals[c], 0.f);
                        unsigned short hi = f2bf_rne(v);
                        Oh[(size_t)m * N + n] = hi;
                        Ol[(size_t)m * N + n] = f2bf_rne(v - bf2f(hi));
                    }
                }
            }
        }
    }
}

// ---------------- Aggregation ----------------
// MODE 2: out = dis[v]*relu(dis[v]*sum + b)   (fp32)
// MODE 3: out = dis[v]*sum + b                (fp32, final)

template <int MODE>
__global__ void agg_kernel(const float* __restrict__ g, const int* __restrict__ row_ptr,
                           const int* __restrict__ col, const float* __restrict__ dis,
                           const float* __restrict__ bias, float* __restrict__ out,
                           int D) {
    int v = blockIdx.x;
    int j = threadIdx.x;
    int s = row_ptr[v], e = row_ptr[v + 1];

    float sum = g[(long)v * D + j];
    int i = s;
    for (; i + 4 <= e; i += 4) {
        int u0 = col[i], u1 = col[i + 1], u2 = col[i + 2], u3 = col[i + 3];
        float f0 = g[(long)u0 * D + j];
        float f1 = g[(long)u1 * D + j];
        float f2 = g[(long)u2 * D + j];
        float f3 = g[(long)u3 * D + j];
        sum += (f0 + f1) + (f2 + f3);
    }
    for (; i < e; ++i)
        sum += g[(long)col[i] * D + j];

    float dv = dis[v];
    float r = dv * sum + bias[j];
    if (MODE == 2) r = fmaxf(r, 0.f) * dv;
    out[(long)v * D + j] = r;
}

// agg-first: out_hi/lo = split(dis[v]*sum) ; g is dis-prescaled
__global__ void agg_split_kernel(const float* __restrict__ g, const int* __restrict__ row_ptr,
                                 const int* __restrict__ col, const float* __restrict__ dis,
                                 unsigned short* __restrict__ oh, unsigned short* __restrict__ ol,
                                 int D) {
    int v = blockIdx.x;
    int j = threadIdx.x;
    int s = row_ptr[v], e = row_ptr[v + 1];

    float sum = g[(long)v * D + j];
    int i = s;
    for (; i + 4 <= e; i += 4) {
        int u0 = col[i], u1 = col[i + 1], u2 = col[i + 2], u3 = col[i + 3];
        float f0 = g[(long)u0 * D + j];
        float f1 = g[(long)u1 * D + j];
        float f2 = g[(long)u2 * D + j];
        float f3 = g[(long)u3 * D + j];
        sum += (f0 + f1) + (f2 + f3);
    }
    for (; i < e; ++i)
        sum += g[(long)col[i] * D + j];

    float r = dis[v] * sum;
    unsigned short hi = f2bf_rne(r);
    oh[(long)v * D + j] = hi;
    ol[(long)v * D + j] = f2bf_rne(r - bf2f(hi));
}

// ---------------- launch ----------------

extern "C" void kernel_launch(void* const* d_in, const int* in_sizes, int n_in,
                              void* d_out, int out_size, void* d_ws, size_t ws_size,
                              hipStream_t stream) {
    const int N = N_NODES, E = N_EDGES;

    const float* x   = (const float*)d_in[0];
    const int*   ei  = (const int*)d_in[1];
    const int*   src = ei;
    const int*   dst = ei + E;
    const float* W1 = (const float*)d_in[2];  const float* b1 = (const float*)d_in[3];
    const float* W2 = (const float*)d_in[4];  const float* b2 = (const float*)d_in[5];
    const float* W3 = (const float*)d_in[6];  const float* b3 = (const float*)d_in[7];
    const float* W4 = (const float*)d_in[8];  const float* b4 = (const float*)d_in[9];
    float* out = (float*)d_out;

    // workspace carve-up
    char* w = (char*)d_ws;
    int*   counts  = (int*)w;    w += align256((size_t)N * 4);
    int*   row_ptr = (int*)w;    w += align256((size_t)(N + 1) * 4);
    int*   cursor  = (int*)w;    w += align256((size_t)N * 4);
    float* dis     = (float*)w;  w += align256((size_t)N * 4);
    int*   bsum    = (int*)w;    w += align256((size_t)64 * 4);
    int*   col     = (int*)w;    w += align256((size_t)E * 4);
    unsigned short* w1h = (unsigned short*)w; w += align256(32768 * 2);
    unsigned short* w1l = (unsigned short*)w; w += align256(32768 * 2);
    unsigned short* w2h = (unsigned short*)w; w += align256(16384 * 2);
    unsigned short* w2l = (unsigned short*)w; w += align256(16384 * 2);
    unsigned short* w3h = (unsigned short*)w; w += align256(16384 * 2);
    unsigned short* w3l = (unsigned short*)w; w += align256(16384 * 2);
    unsigned short* w4h = (unsigned short*)w; w += align256(32768 * 2);
    unsigned short* w4l = (unsigned short*)w; w += align256(32768 * 2);
    // arenas (aliased across phases)
    char* S1 = w;  w += align256((size_t)N * 128 * 4);   // xs f32 | h3h bf16[N,256]
    char* S2 = w;  w += align256((size_t)N * 128 * 2);   // t1h | g2 f32[N,64] | t3h+t3l
    char* S3 = w;  w += align256((size_t)N * 128 * 2);   // t1l | h2s f32[N,64]
    char* S4 = w;  w += align256((size_t)N * 256 * 2);   // h1h | h3l
    char* S5 = w;  w += align256((size_t)N * 256 * 2);   // h1l | g4 f32[N,128]

    float* xs   = (float*)S1;
    unsigned short* t1h = (unsigned short*)S2;
    unsigned short* t1l = (unsigned short*)S3;
    unsigned short* h1h = (unsigned short*)S4;
    unsigned short* h1l = (unsigned short*)S5;
    float* g2   = (float*)S2;
    float* h2s  = (float*)S3;
    unsigned short* t3h = (unsigned short*)S2;
    unsigned short* t3l = (unsigned short*)(S2 + (size_t)N * 64 * 2);
    unsigned short* h3h = (unsigned short*)S1;
    unsigned short* h3l = (unsigned short*)S4;
    float* g4   = (float*)S5;

    // ---- CSR build ----
    const int nb = (N + 1023) / 1024;
    hipMemsetAsync(counts, 0, (size_t)N * 4, stream);
    count_kernel<<<(E + 255) / 256, 256, 0, stream>>>(dst, counts, E);
    scan1_kernel<<<nb, 1024, 0, stream>>>(counts, row_ptr, bsum, N);
    scan2_kernel<<<1, 64, 0, stream>>>(bsum, nb);
    scan3_kernel<<<(N + 255) / 256, 256, 0, stream>>>(row_ptr, bsum, N);
    prep_kernel<<<(N + 255) / 256, 256, 0, stream>>>(row_ptr, counts, cursor, dis, N);
    fill_kernel<<<(E + 255) / 256, 256, 0, stream>>>(src, dst, cursor, col, E);

    // ---- pack weights (hi/lo, fragment order) ----
    pack_w<<<(4096 + 255) / 256, 256, 0, stream>>>(W1, w1h, w1l, 128, 256);
    pack_w<<<(2048 + 255) / 256, 256, 0, stream>>>(W2, w2h, w2l, 256, 64);
    pack_w<<<(2048 + 255) / 256, 256, 0, stream>>>(W3, w3h, w3l, 64, 256);
    pack_w<<<(4096 + 255) / 256, 256, 0, stream>>>(W4, w4h, w4l, 256, 128);

    const int gy = (N + 127) / 128;   // 391

    // ---- layer 1 (agg-first): xs = dis*x ; t1 = Âs xs ; h1 = relu(t1 @ W1 + b1) ----
    scale_kernel<<<(N * 32 + 255) / 256, 256, 0, stream>>>(x, dis, xs, N * 32);
    agg_split_kernel<<<N, 128, 0, stream>>>(xs, row_ptr, col, dis, t1h, t1l, 128);
    mfma_gemm<1><<<dim3(4, gy), 256, 0, stream>>>(t1h, t1l, w1h, w1l, dis, b1,
                                                  nullptr, h1h, h1l, N, 256, 128);

    // ---- layer 2 (agg-after): g2 = dis*(h1 @ W2) ; h2s = dis*relu(agg + b2) ----
    mfma_gemm<0><<<dim3(1, gy), 256, 0, stream>>>(h1h, h1l, w2h, w2l, dis, b2,
                                                  g2, nullptr, nullptr, N, 64, 256);
    agg_kernel<2><<<N, 64, 0, stream>>>(g2, row_ptr, col, dis, b2, h2s, 64);

    // ---- layer 3 (agg-first): t3 = Âs h2s ; h3 = relu(t3 @ W3 + b3) ----
    agg_split_kernel<<<N, 64, 0, stream>>>(h2s, row_ptr, col, dis, t3h, t3l, 64);
    mfma_gemm<1><<<dim3(4, gy), 256, 0, stream>>>(t3h, t3l, w3h, w3l, dis, b3,
                                                  nullptr, h3h, h3l, N, 256, 64);

    // ---- layer 4 (agg-after): g4 = dis*(h3 @ W4) ; out = agg + b4 ----
    mfma_gemm<0><<<dim3(2, gy), 256, 0, stream>>>(h3h, h3l, w4h, w4l, dis, b4,
                                                  g4, nullptr, nullptr, N, 128, 256);
    agg_kernel<3><<<N, 128, 0, stream>>>(g4, row_ptr, col, dis, b4, out, 128);
}

// Round 5
// 390.636 us; speedup vs baseline: 1.7197x; 1.0645x over previous
//
#include <hip/hip_runtime.h>

#define N_NODES 50000
#define N_EDGES 800000

static inline size_t align256(size_t x) { return (x + 255) & ~(size_t)255; }

typedef short bf16x8 __attribute__((ext_vector_type(8)));   // 8 bf16 in 4 VGPRs
typedef float f32x4 __attribute__((ext_vector_type(4)));

__device__ __forceinline__ unsigned short f2bf_rne(float v) {
    unsigned u = __builtin_bit_cast(unsigned, v);
    u += 0x7fffu + ((u >> 16) & 1u);
    return (unsigned short)(u >> 16);
}
__device__ __forceinline__ float bf2f(unsigned short h) {
    unsigned u = (unsigned)h << 16;
    return __builtin_bit_cast(float, u);
}

// ---------------- CSR build ----------------

__global__ void count_kernel(const int* __restrict__ dst, int* __restrict__ counts, int E) {
    int e = blockIdx.x * blockDim.x + threadIdx.x;
    if (e < E) atomicAdd(&counts[dst[e]], 1);
}

__global__ void scan1_kernel(const int* __restrict__ counts, int* __restrict__ row_ptr,
                             int* __restrict__ bsum, int n) {
    __shared__ int sd[1024];
    int i = blockIdx.x * 1024 + threadIdx.x;
    int v = (i < n) ? counts[i] : 0;
    sd[threadIdx.x] = v;
    __syncthreads();
    #pragma unroll
    for (int off = 1; off < 1024; off <<= 1) {
        int t = 0;
        if ((int)threadIdx.x >= off) t = sd[threadIdx.x - off];
        __syncthreads();
        sd[threadIdx.x] += t;
        __syncthreads();
    }
    if (i < n) row_ptr[i + 1] = sd[threadIdx.x];
    if (threadIdx.x == 1023) bsum[blockIdx.x] = sd[1023];
}

__global__ void scan2_kernel(int* __restrict__ bsum, int nb) {
    if (threadIdx.x == 0) {
        int acc = 0;
        for (int b = 0; b < nb; ++b) { int t = bsum[b]; bsum[b] = acc; acc += t; }
    }
}

// scan finalize + cursor + dis (prep merged)
__global__ void scan3_kernel(int* __restrict__ row_ptr, const int* __restrict__ bsum,
                             const int* __restrict__ counts, int* __restrict__ cursor,
                             float* __restrict__ dis, int n) {
    int i = blockIdx.x * blockDim.x + threadIdx.x;
    if (i < n) {
        int rp = row_ptr[i + 1] + bsum[i >> 10];
        row_ptr[i + 1] = rp;
        if (i + 1 < n) cursor[i + 1] = rp;
        dis[i] = rsqrtf((float)(counts[i] + 1));
        if (i == 0) { row_ptr[0] = 0; cursor[0] = 0; }
    }
}

__global__ void fill_kernel(const int* __restrict__ src, const int* __restrict__ dst,
                            int* __restrict__ cursor, int* __restrict__ col, int E) {
    int e = blockIdx.x * blockDim.x + threadIdx.x;
    if (e < E) {
        int p = atomicAdd(&cursor[dst[e]], 1);
        col[p] = src[e];
    }
}

// ---------------- W packing: fragment-order hi/lo bf16 ----------------

__global__ void pack_w(const float* __restrict__ W, unsigned short* __restrict__ Ph,
                       unsigned short* __restrict__ Pl, int K, int N) {
    int id = blockIdx.x * blockDim.x + threadIdx.x;
    int total = (K >> 5) * (N >> 4) * 64;
    if (id >= total) return;
    int l = id & 63;
    int f = id >> 6;
    int nf16 = N >> 4;
    int ks = f / nf16, nf = f - ks * nf16;
    int k0 = ks * 32 + (l >> 4) * 8;
    int n  = nf * 16 + (l & 15);
    #pragma unroll
    for (int j = 0; j < 8; ++j) {
        float v = W[(size_t)(k0 + j) * N + n];
        unsigned short hi = f2bf_rne(v);
        Ph[(size_t)id * 8 + j] = hi;
        Pl[(size_t)id * 8 + j] = f2bf_rne(v - bf2f(hi));
    }
}

// ---------------- MFMA GEMM (bf16x3 split) ----------------
// EPI 0: Gf[m,:] = dis[m]*acc            (fp32, feeds agg-after)
// EPI 1: Oh/Ol   = split(relu(acc+bias)) (hi/lo bf16)
// Tile 128x64, 256 threads = 4 waves. K, N compile-time.

template <int EPI, int K, int N>
__global__ __launch_bounds__(256) void mfma_gemm(
    const unsigned short* __restrict__ Ah, const unsigned short* __restrict__ Al,
    const unsigned short* __restrict__ Bh, const unsigned short* __restrict__ Bl,
    const float* __restrict__ dis, const float* __restrict__ bias,
    float* __restrict__ Gf, unsigned short* __restrict__ Oh, unsigned short* __restrict__ Ol,
    int M) {

    int t = threadIdx.x;
    int w = t >> 6, l = t & 63;
    int m0 = blockIdx.y * 128 + w * 32;
    int n0 = blockIdx.x * 64;

    int lrow = l & 15;
    int lk   = (l >> 4) * 8;

    int r0 = m0 + lrow, r1 = m0 + 16 + lrow;
    bool ok0 = r0 < M, ok1 = r1 < M;

    const unsigned short* pAh0 = Ah + (size_t)r0 * K + lk;
    const unsigned short* pAl0 = Al + (size_t)r0 * K + lk;
    const unsigned short* pAh1 = Ah + (size_t)r1 * K + lk;
    const unsigned short* pAl1 = Al + (size_t)r1 * K + lk;

    const int nf16 = N >> 4;
    const unsigned short* pBh = Bh + (size_t)(n0 >> 4) * 512 + (size_t)l * 8;
    const unsigned short* pBl = Bl + (size_t)(n0 >> 4) * 512 + (size_t)l * 8;

    f32x4 acc[2][4] = {};
    bf16x8 z8 = {0, 0, 0, 0, 0, 0, 0, 0};

    #pragma unroll
    for (int kt = 0; kt < K; kt += 32) {
        bf16x8 ah0 = ok0 ? *(const bf16x8*)(pAh0 + kt) : z8;
        bf16x8 al0 = ok0 ? *(const bf16x8*)(pAl0 + kt) : z8;
        bf16x8 ah1 = ok1 ? *(const bf16x8*)(pAh1 + kt) : z8;
        bf16x8 al1 = ok1 ? *(const bf16x8*)(pAl1 + kt) : z8;

        const size_t boff = (size_t)(kt >> 5) * nf16 * 512;
        #pragma unroll
        for (int c = 0; c < 4; ++c) {
            bf16x8 bh = *(const bf16x8*)(pBh + boff + (size_t)c * 512);
            bf16x8 bl = *(const bf16x8*)(pBl + boff + (size_t)c * 512);
            acc[0][c] = __builtin_amdgcn_mfma_f32_16x16x32_bf16(ah0, bh, acc[0][c], 0, 0, 0);
            acc[0][c] = __builtin_amdgcn_mfma_f32_16x16x32_bf16(al0, bh, acc[0][c], 0, 0, 0);
            acc[0][c] = __builtin_amdgcn_mfma_f32_16x16x32_bf16(ah0, bl, acc[0][c], 0, 0, 0);
            acc[1][c] = __builtin_amdgcn_mfma_f32_16x16x32_bf16(ah1, bh, acc[1][c], 0, 0, 0);
            acc[1][c] = __builtin_amdgcn_mfma_f32_16x16x32_bf16(al1, bh, acc[1][c], 0, 0, 0);
            acc[1][c] = __builtin_amdgcn_mfma_f32_16x16x32_bf16(ah1, bl, acc[1][c], 0, 0, 0);
        }
    }

    float bvals[4];
    if (EPI == 1) {
        #pragma unroll
        for (int c = 0; c < 4; ++c) bvals[c] = bias[n0 + c * 16 + lrow];
    }

    #pragma unroll
    for (int rf = 0; rf < 2; ++rf) {
        int mb = m0 + rf * 16 + (l >> 4) * 4;
        #pragma unroll
        for (int r = 0; r < 4; ++r) {
            int m = mb + r;
            if (m < M) {
                if (EPI == 0) {
                    float s = dis[m];
                    #pragma unroll
                    for (int c = 0; c < 4; ++c) {
                        int n = n0 + c * 16 + lrow;
                        Gf[(size_t)m * N + n] = s * acc[rf][c][r];
                    }
                } else {
                    #pragma unroll
                    for (int c = 0; c < 4; ++c) {
                        int n = n0 + c * 16 + lrow;
                        float v = fmaxf(acc[rf][c][r] + bvals[c], 0.f);
                        unsigned short hi = f2bf_rne(v);
                        Oh[(size_t)m * N + n] = hi;
                        Ol[(size_t)m * N + n] = f2bf_rne(v - bf2f(hi));
                    }
                }
            }
        }
    }
}

// ---------------- Aggregation (float4-vectorized gather) ----------------
// DQ = D/4 lanes per node; block = 256 threads = (256/DQ) nodes.
// MODE 0: input prescaled;  out split(dis[v]*sum)            -> oh/ol bf16
// MODE 1: input x, per-edge dis[u] scale; out split(dis[v]*sum) -> oh/ol
// MODE 2: input prescaled;  out = dis*relu(dis*sum + b)      -> fp32
// MODE 3: input prescaled;  out = dis*sum + b                -> fp32

template <int MODE, int DQ>
__global__ __launch_bounds__(256) void agg4(
    const float* __restrict__ g, const int* __restrict__ row_ptr,
    const int* __restrict__ col, const float* __restrict__ dis,
    const float* __restrict__ bias, float* __restrict__ outf,
    unsigned short* __restrict__ oh, unsigned short* __restrict__ ol) {
    const int NPB = 256 / DQ;
    int t = threadIdx.x;
    int nl = t / DQ, c = t % DQ;
    int v = blockIdx.x * NPB + nl;
    const float4* g4 = (const float4*)g;
    size_t rowq = (size_t)v * DQ + c;

    float4 sum = g4[rowq];                 // self-loop term
    if (MODE == 1) {
        float sv = dis[v];
        sum.x *= sv; sum.y *= sv; sum.z *= sv; sum.w *= sv;
    }

    int s = row_ptr[v], e = row_ptr[v + 1];
    int i = s;
    for (; i + 4 <= e; i += 4) {
        int u0 = col[i], u1 = col[i + 1], u2 = col[i + 2], u3 = col[i + 3];
        float4 f0 = g4[(size_t)u0 * DQ + c];
        float4 f1 = g4[(size_t)u1 * DQ + c];
        float4 f2 = g4[(size_t)u2 * DQ + c];
        float4 f3 = g4[(size_t)u3 * DQ + c];
        if (MODE == 1) {
            float d0 = dis[u0], d1 = dis[u1], d2 = dis[u2], d3 = dis[u3];
            sum.x += d0 * f0.x + d1 * f1.x + d2 * f2.x + d3 * f3.x;
            sum.y += d0 * f0.y + d1 * f1.y + d2 * f2.y + d3 * f3.y;
            sum.z += d0 * f0.z + d1 * f1.z + d2 * f2.z + d3 * f3.z;
            sum.w += d0 * f0.w + d1 * f1.w + d2 * f2.w + d3 * f3.w;
        } else {
            sum.x += (f0.x + f1.x) + (f2.x + f3.x);
            sum.y += (f0.y + f1.y) + (f2.y + f3.y);
            sum.z += (f0.z + f1.z) + (f2.z + f3.z);
            sum.w += (f0.w + f1.w) + (f2.w + f3.w);
        }
    }
    for (; i < e; ++i) {
        int u = col[i];
        float4 f = g4[(size_t)u * DQ + c];
        if (MODE == 1) {
            float d = dis[u];
            sum.x += d * f.x; sum.y += d * f.y; sum.z += d * f.z; sum.w += d * f.w;
        } else {
            sum.x += f.x; sum.y += f.y; sum.z += f.z; sum.w += f.w;
        }
    }

    float dv = dis[v];
    if (MODE <= 1) {
        float r0 = dv * sum.x, r1 = dv * sum.y, r2 = dv * sum.z, r3 = dv * sum.w;
        ushort4 h, lo;
        h.x = f2bf_rne(r0); lo.x = f2bf_rne(r0 - bf2f(h.x));
        h.y = f2bf_rne(r1); lo.y = f2bf_rne(r1 - bf2f(h.y));
        h.z = f2bf_rne(r2); lo.z = f2bf_rne(r2 - bf2f(h.z));
        h.w = f2bf_rne(r3); lo.w = f2bf_rne(r3 - bf2f(h.w));
        ((ushort4*)oh)[rowq] = h;
        ((ushort4*)ol)[rowq] = lo;
    } else {
        float4 b4 = ((const float4*)bias)[c];
        float r0 = dv * sum.x + b4.x, r1 = dv * sum.y + b4.y;
        float r2 = dv * sum.z + b4.z, r3 = dv * sum.w + b4.w;
        if (MODE == 2) {
            r0 = fmaxf(r0, 0.f) * dv; r1 = fmaxf(r1, 0.f) * dv;
            r2 = fmaxf(r2, 0.f) * dv; r3 = fmaxf(r3, 0.f) * dv;
        }
        ((float4*)outf)[rowq] = make_float4(r0, r1, r2, r3);
    }
}

// ---------------- launch ----------------

extern "C" void kernel_launch(void* const* d_in, const int* in_sizes, int n_in,
                              void* d_out, int out_size, void* d_ws, size_t ws_size,
                              hipStream_t stream) {
    const int N = N_NODES, E = N_EDGES;

    const float* x   = (const float*)d_in[0];
    const int*   ei  = (const int*)d_in[1];
    const int*   src = ei;
    const int*   dst = ei + E;
    const float* W1 = (const float*)d_in[2];  const float* b1 = (const float*)d_in[3];
    const float* W2 = (const float*)d_in[4];  const float* b2 = (const float*)d_in[5];
    const float* W3 = (const float*)d_in[6];  const float* b3 = (const float*)d_in[7];
    const float* W4 = (const float*)d_in[8];  const float* b4 = (const float*)d_in[9];
    float* out = (float*)d_out;

    // workspace carve-up
    char* w = (char*)d_ws;
    int*   counts  = (int*)w;    w += align256((size_t)N * 4);
    int*   row_ptr = (int*)w;    w += align256((size_t)(N + 1) * 4);
    int*   cursor  = (int*)w;    w += align256((size_t)N * 4);
    float* dis     = (float*)w;  w += align256((size_t)N * 4);
    int*   bsum    = (int*)w;    w += align256((size_t)64 * 4);
    int*   col     = (int*)w;    w += align256((size_t)E * 4);
    unsigned short* w1h = (unsigned short*)w; w += align256(32768 * 2);
    unsigned short* w1l = (unsigned short*)w; w += align256(32768 * 2);
    unsigned short* w2h = (unsigned short*)w; w += align256(16384 * 2);
    unsigned short* w2l = (unsigned short*)w; w += align256(16384 * 2);
    unsigned short* w3h = (unsigned short*)w; w += align256(16384 * 2);
    unsigned short* w3l = (unsigned short*)w; w += align256(16384 * 2);
    unsigned short* w4h = (unsigned short*)w; w += align256(32768 * 2);
    unsigned short* w4l = (unsigned short*)w; w += align256(32768 * 2);
    // arenas (aliased across phases)
    char* P1 = w;  w += align256((size_t)N * 128 * 2);   // t1h | t3h+t3l
    char* P2 = w;  w += align256((size_t)N * 128 * 2);   // t1l | g2 f32[N,64]
    char* P3 = w;  w += align256((size_t)N * 256 * 2);   // h1h | h3h
    char* P4 = w;  w += align256((size_t)N * 256 * 2);   // h1l | h3l
    char* P5 = w;  w += align256((size_t)N * 128 * 4);   // h2s f32[N,64] | gg4 f32[N,128]

    unsigned short* t1h = (unsigned short*)P1;
    unsigned short* t1l = (unsigned short*)P2;
    unsigned short* h1h = (unsigned short*)P3;
    unsigned short* h1l = (unsigned short*)P4;
    float* g2   = (float*)P2;
    float* h2s  = (float*)P5;
    unsigned short* t3h = (unsigned short*)P1;
    unsigned short* t3l = (unsigned short*)(P1 + (size_t)N * 64 * 2);
    unsigned short* h3h = (unsigned short*)P3;
    unsigned short* h3l = (unsigned short*)P4;
    float* gg4  = (float*)P5;

    // ---- CSR build ----
    const int nb = (N + 1023) / 1024;
    hipMemsetAsync(counts, 0, (size_t)N * 4, stream);
    count_kernel<<<(E + 255) / 256, 256, 0, stream>>>(dst, counts, E);
    scan1_kernel<<<nb, 1024, 0, stream>>>(counts, row_ptr, bsum, N);
    scan2_kernel<<<1, 64, 0, stream>>>(bsum, nb);
    scan3_kernel<<<(N + 255) / 256, 256, 0, stream>>>(row_ptr, bsum, counts, cursor, dis, N);
    fill_kernel<<<(E + 255) / 256, 256, 0, stream>>>(src, dst, cursor, col, E);

    // ---- pack weights ----
    pack_w<<<(4096 + 255) / 256, 256, 0, stream>>>(W1, w1h, w1l, 128, 256);
    pack_w<<<(2048 + 255) / 256, 256, 0, stream>>>(W2, w2h, w2l, 256, 64);
    pack_w<<<(2048 + 255) / 256, 256, 0, stream>>>(W3, w3h, w3l, 64, 256);
    pack_w<<<(4096 + 255) / 256, 256, 0, stream>>>(W4, w4h, w4l, 256, 128);

    const int gy = (N + 127) / 128;   // 391

    // ---- layer 1 (agg-first): t1 = Âs (dis*x) ; h1 = relu(t1 @ W1 + b1) ----
    agg4<1, 32><<<N / 8, 256, 0, stream>>>(x, row_ptr, col, dis, nullptr, nullptr, t1h, t1l);
    mfma_gemm<1, 128, 256><<<dim3(4, gy), 256, 0, stream>>>(t1h, t1l, w1h, w1l, dis, b1,
                                                            nullptr, h1h, h1l, N);

    // ---- layer 2 (agg-after): g2 = dis*(h1 @ W2) ; h2s = dis*relu(agg + b2) ----
    mfma_gemm<0, 256, 64><<<dim3(1, gy), 256, 0, stream>>>(h1h, h1l, w2h, w2l, dis, b2,
                                                           g2, nullptr, nullptr, N);
    agg4<2, 16><<<N / 16, 256, 0, stream>>>(g2, row_ptr, col, dis, b2, h2s, nullptr, nullptr);

    // ---- layer 3 (agg-first): t3 = Âs h2s ; h3 = relu(t3 @ W3 + b3) ----
    agg4<0, 16><<<N / 16, 256, 0, stream>>>(h2s, row_ptr, col, dis, nullptr, nullptr, t3h, t3l);
    mfma_gemm<1, 64, 256><<<dim3(4, gy), 256, 0, stream>>>(t3h, t3l, w3h, w3l, dis, b3,
                                                           nullptr, h3h, h3l, N);

    // ---- layer 4 (agg-after): gg4 = dis*(h3 @ W4) ; out = agg + b4 ----
    mfma_gemm<0, 256, 128><<<dim3(2, gy), 256, 0, stream>>>(h3h, h3l, w4h, w4l, dis, b4,
                                                            gg4, nullptr, nullptr, N);
    agg4<3, 32><<<N / 8, 256, 0, stream>>>(gg4, row_ptr, col, dis, b4, out, nullptr, nullptr);
}

// Round 6
// 296.417 us; speedup vs baseline: 2.2664x; 1.3179x over previous
//
#include <hip/hip_runtime.h>

#define N_NODES 50000
#define N_EDGES 800000

static inline size_t align256(size_t x) { return (x + 255) & ~(size_t)255; }

typedef _Float16 f16x8 __attribute__((ext_vector_type(8)));   // 8 fp16 in 4 VGPRs
typedef _Float16 f16x4 __attribute__((ext_vector_type(4)));
typedef float f32x4 __attribute__((ext_vector_type(4)));

// ---------------- CSR build ----------------

// rank[e] = position of edge e within its destination's bucket
__global__ void count_kernel(const int* __restrict__ dst, int* __restrict__ counts,
                             int* __restrict__ rank, int E) {
    int e = blockIdx.x * blockDim.x + threadIdx.x;
    if (e < E) rank[e] = atomicAdd(&counts[dst[e]], 1);
}

__global__ void scan1_kernel(const int* __restrict__ counts, int* __restrict__ row_ptr,
                             int* __restrict__ bsum, int n) {
    __shared__ int sd[1024];
    int i = blockIdx.x * 1024 + threadIdx.x;
    int v = (i < n) ? counts[i] : 0;
    sd[threadIdx.x] = v;
    __syncthreads();
    #pragma unroll
    for (int off = 1; off < 1024; off <<= 1) {
        int t = 0;
        if ((int)threadIdx.x >= off) t = sd[threadIdx.x - off];
        __syncthreads();
        sd[threadIdx.x] += t;
        __syncthreads();
    }
    if (i < n) row_ptr[i + 1] = sd[threadIdx.x];
    if (threadIdx.x == 1023) bsum[blockIdx.x] = sd[1023];
}

__global__ void scan2_kernel(int* __restrict__ bsum, int nb) {
    if (threadIdx.x == 0) {
        int acc = 0;
        for (int b = 0; b < nb; ++b) { int t = bsum[b]; bsum[b] = acc; acc += t; }
    }
}

__global__ void scan3_kernel(int* __restrict__ row_ptr, const int* __restrict__ bsum,
                             const int* __restrict__ counts, float* __restrict__ dis, int n) {
    int i = blockIdx.x * blockDim.x + threadIdx.x;
    if (i < n) {
        row_ptr[i + 1] += bsum[i >> 10];
        dis[i] = rsqrtf((float)(counts[i] + 1));
        if (i == 0) row_ptr[0] = 0;
    }
}

// no atomic: slot is row_ptr[dst] + rank  (store is fire-and-forget)
__global__ void fill_kernel(const int* __restrict__ src, const int* __restrict__ dst,
                            const int* __restrict__ rank, const int* __restrict__ row_ptr,
                            int* __restrict__ col, int E) {
    int e = blockIdx.x * blockDim.x + threadIdx.x;
    if (e < E) col[row_ptr[dst[e]] + rank[e]] = src[e];
}

// xs_h[v,:] = fp16(dis[v] * x[v,:])   (D = 128; one half4 per thread)
__global__ void xs_half_kernel(const float* __restrict__ x, const float* __restrict__ dis,
                               _Float16* __restrict__ xs, int nq) {
    int q = blockIdx.x * blockDim.x + threadIdx.x;
    if (q < nq) {
        int v = q >> 5;                      // 32 quads per row
        float s = dis[v];
        float4 t = *(const float4*)(x + (size_t)q * 4);
        f16x4 h;
        h.x = (_Float16)(s * t.x); h.y = (_Float16)(s * t.y);
        h.z = (_Float16)(s * t.z); h.w = (_Float16)(s * t.w);
        ((f16x4*)xs)[q] = h;
    }
}

// ---------------- W packing: fragment-order hi/lo fp16 ----------------

__global__ void pack_w(const float* __restrict__ W, _Float16* __restrict__ Ph,
                       _Float16* __restrict__ Pl, int K, int N) {
    int id = blockIdx.x * blockDim.x + threadIdx.x;
    int total = (K >> 5) * (N >> 4) * 64;
    if (id >= total) return;
    int l = id & 63;
    int f = id >> 6;
    int nf16 = N >> 4;
    int ks = f / nf16, nf = f - ks * nf16;
    int k0 = ks * 32 + (l >> 4) * 8;
    int n  = nf * 16 + (l & 15);
    #pragma unroll
    for (int j = 0; j < 8; ++j) {
        float v = W[(size_t)(k0 + j) * N + n];
        _Float16 hi = (_Float16)v;
        Ph[(size_t)id * 8 + j] = hi;
        Pl[(size_t)id * 8 + j] = (_Float16)(v - (float)hi);
    }
}

// ---------------- MFMA GEMM (fp16 split x3): G = epi(A @ W) ----------------
// A as hi/lo fp16 [M,K] row-major; W pre-packed hi/lo fragments.
// EPI 0: G16[m,:] = fp16(dis[m]*acc)       (feeds agg-after)
// EPI 1: Oh/Ol    = split(relu(acc+bias))  (hi/lo fp16, feeds next GEMM)
// Tile 128x64, 256 threads = 4 waves. K, N compile-time. M % 16 == 0.

template <int EPI, int K, int N>
__global__ __launch_bounds__(256) void mfma_gemm(
    const _Float16* __restrict__ Ah, const _Float16* __restrict__ Al,
    const _Float16* __restrict__ Bh, const _Float16* __restrict__ Bl,
    const float* __restrict__ dis, const float* __restrict__ bias,
    _Float16* __restrict__ G16, _Float16* __restrict__ Oh, _Float16* __restrict__ Ol,
    int M) {

    int t = threadIdx.x;
    int w = t >> 6, l = t & 63;
    int m0 = blockIdx.y * 128 + w * 32;
    int n0 = blockIdx.x * 64;

    int lrow = l & 15;
    int lk   = (l >> 4) * 8;

    int r0 = m0 + lrow, r1 = m0 + 16 + lrow;
    bool ok0 = r0 < M, ok1 = r1 < M;

    const _Float16* pAh0 = Ah + (size_t)r0 * K + lk;
    const _Float16* pAl0 = Al + (size_t)r0 * K + lk;
    const _Float16* pAh1 = Ah + (size_t)r1 * K + lk;
    const _Float16* pAl1 = Al + (size_t)r1 * K + lk;

    const int nf16 = N >> 4;
    const _Float16* pBh = Bh + (size_t)(n0 >> 4) * 512 + (size_t)l * 8;
    const _Float16* pBl = Bl + (size_t)(n0 >> 4) * 512 + (size_t)l * 8;

    f32x4 acc[2][4] = {};
    f16x8 z8 = {0, 0, 0, 0, 0, 0, 0, 0};

    #pragma unroll
    for (int kt = 0; kt < K; kt += 32) {
        f16x8 ah0 = ok0 ? *(const f16x8*)(pAh0 + kt) : z8;
        f16x8 al0 = ok0 ? *(const f16x8*)(pAl0 + kt) : z8;
        f16x8 ah1 = ok1 ? *(const f16x8*)(pAh1 + kt) : z8;
        f16x8 al1 = ok1 ? *(const f16x8*)(pAl1 + kt) : z8;

        const size_t boff = (size_t)(kt >> 5) * nf16 * 512;
        #pragma unroll
        for (int c = 0; c < 4; ++c) {
            f16x8 bh = *(const f16x8*)(pBh + boff + (size_t)c * 512);
            f16x8 bl = *(const f16x8*)(pBl + boff + (size_t)c * 512);
            acc[0][c] = __builtin_amdgcn_mfma_f32_16x16x32_f16(ah0, bh, acc[0][c], 0, 0, 0);
            acc[0][c] = __builtin_amdgcn_mfma_f32_16x16x32_f16(al0, bh, acc[0][c], 0, 0, 0);
            acc[0][c] = __builtin_amdgcn_mfma_f32_16x16x32_f16(ah0, bl, acc[0][c], 0, 0, 0);
            acc[1][c] = __builtin_amdgcn_mfma_f32_16x16x32_f16(ah1, bh, acc[1][c], 0, 0, 0);
            acc[1][c] = __builtin_amdgcn_mfma_f32_16x16x32_f16(al1, bh, acc[1][c], 0, 0, 0);
            acc[1][c] = __builtin_amdgcn_mfma_f32_16x16x32_f16(ah1, bl, acc[1][c], 0, 0, 0);
        }
    }

    float bvals[4];
    if (EPI == 1) {
        #pragma unroll
        for (int c = 0; c < 4; ++c) bvals[c] = bias[n0 + c * 16 + lrow];
    }

    #pragma unroll
    for (int rf = 0; rf < 2; ++rf) {
        int mb = m0 + rf * 16 + (l >> 4) * 4;
        #pragma unroll
        for (int r = 0; r < 4; ++r) {
            int m = mb + r;
            if (m < M) {
                if (EPI == 0) {
                    float s = dis[m];
                    #pragma unroll
                    for (int c = 0; c < 4; ++c) {
                        int n = n0 + c * 16 + lrow;
                        G16[(size_t)m * N + n] = (_Float16)(s * acc[rf][c][r]);
                    }
                } else {
                    #pragma unroll
                    for (int c = 0; c < 4; ++c) {
                        int n = n0 + c * 16 + lrow;
                        float v = fmaxf(acc[rf][c][r] + bvals[c], 0.f);
                        _Float16 hi = (_Float16)v;
                        Oh[(size_t)m * N + n] = hi;
                        Ol[(size_t)m * N + n] = (_Float16)(v - (float)hi);
                    }
                }
            }
        }
    }
}

// ---------------- Aggregation (fp16 gather, fp32 accumulate) ----------------
// DQ = D/4 lanes per node (half4 units); block = 256 threads = (256/DQ) nodes.
// Input g is fp16, dis-prescaled where applicable.
// MODE 0: out split(dis[v]*sum)             -> oh/ol fp16   (feeds GEMM)
// MODE 2: out fp16(dis*relu(dis*sum + b))   -> o16          (prescaled for next agg)
// MODE 3: out fp32(dis*sum + b)             -> outf         (final layer)

template <int MODE, int DQ>
__global__ __launch_bounds__(256) void agg4(
    const _Float16* __restrict__ g, const int* __restrict__ row_ptr,
    const int* __restrict__ col, const float* __restrict__ dis,
    const float* __restrict__ bias, float* __restrict__ outf,
    _Float16* __restrict__ o16, _Float16* __restrict__ oh, _Float16* __restrict__ ol) {
    const int NPB = 256 / DQ;
    int t = threadIdx.x;
    int nl = t / DQ, c = t % DQ;
    int v = blockIdx.x * NPB + nl;
    const f16x4* g4 = (const f16x4*)g;
    size_t rowq = (size_t)v * DQ + c;

    f16x4 sf = g4[rowq];                 // self-loop term
    float4 sum = make_float4((float)sf.x, (float)sf.y, (float)sf.z, (float)sf.w);

    int s = row_ptr[v], e = row_ptr[v + 1];
    int i = s;
    for (; i + 4 <= e; i += 4) {
        int u0 = col[i], u1 = col[i + 1], u2 = col[i + 2], u3 = col[i + 3];
        f16x4 f0 = g4[(size_t)u0 * DQ + c];
        f16x4 f1 = g4[(size_t)u1 * DQ + c];
        f16x4 f2 = g4[(size_t)u2 * DQ + c];
        f16x4 f3 = g4[(size_t)u3 * DQ + c];
        sum.x += ((float)f0.x + (float)f1.x) + ((float)f2.x + (float)f3.x);
        sum.y += ((float)f0.y + (float)f1.y) + ((float)f2.y + (float)f3.y);
        sum.z += ((float)f0.z + (float)f1.z) + ((float)f2.z + (float)f3.z);
        sum.w += ((float)f0.w + (float)f1.w) + ((float)f2.w + (float)f3.w);
    }
    for (; i < e; ++i) {
        f16x4 f = g4[(size_t)col[i] * DQ + c];
        sum.x += (float)f.x; sum.y += (float)f.y;
        sum.z += (float)f.z; sum.w += (float)f.w;
    }

    float dv = dis[v];
    if (MODE == 0) {
        float r0 = dv * sum.x, r1 = dv * sum.y, r2 = dv * sum.z, r3 = dv * sum.w;
        f16x4 h, lo;
        h.x = (_Float16)r0; lo.x = (_Float16)(r0 - (float)h.x);
        h.y = (_Float16)r1; lo.y = (_Float16)(r1 - (float)h.y);
        h.z = (_Float16)r2; lo.z = (_Float16)(r2 - (float)h.z);
        h.w = (_Float16)r3; lo.w = (_Float16)(r3 - (float)h.w);
        ((f16x4*)oh)[rowq] = h;
        ((f16x4*)ol)[rowq] = lo;
    } else {
        float4 b4 = ((const float4*)bias)[c];
        float r0 = dv * sum.x + b4.x, r1 = dv * sum.y + b4.y;
        float r2 = dv * sum.z + b4.z, r3 = dv * sum.w + b4.w;
        if (MODE == 2) {
            r0 = fmaxf(r0, 0.f) * dv; r1 = fmaxf(r1, 0.f) * dv;
            r2 = fmaxf(r2, 0.f) * dv; r3 = fmaxf(r3, 0.f) * dv;
            f16x4 h;
            h.x = (_Float16)r0; h.y = (_Float16)r1;
            h.z = (_Float16)r2; h.w = (_Float16)r3;
            ((f16x4*)o16)[rowq] = h;
        } else {
            ((float4*)outf)[rowq] = make_float4(r0, r1, r2, r3);
        }
    }
}

// ---------------- launch ----------------

extern "C" void kernel_launch(void* const* d_in, const int* in_sizes, int n_in,
                              void* d_out, int out_size, void* d_ws, size_t ws_size,
                              hipStream_t stream) {
    const int N = N_NODES, E = N_EDGES;

    const float* x   = (const float*)d_in[0];
    const int*   ei  = (const int*)d_in[1];
    const int*   src = ei;
    const int*   dst = ei + E;
    const float* W1 = (const float*)d_in[2];  const float* b1 = (const float*)d_in[3];
    const float* W2 = (const float*)d_in[4];  const float* b2 = (const float*)d_in[5];
    const float* W3 = (const float*)d_in[6];  const float* b3 = (const float*)d_in[7];
    const float* W4 = (const float*)d_in[8];  const float* b4 = (const float*)d_in[9];
    float* out = (float*)d_out;

    // workspace carve-up
    char* w = (char*)d_ws;
    int*   counts  = (int*)w;    w += align256((size_t)N * 4);
    int*   row_ptr = (int*)w;    w += align256((size_t)(N + 1) * 4);
    float* dis     = (float*)w;  w += align256((size_t)N * 4);
    int*   bsum    = (int*)w;    w += align256((size_t)64 * 4);
    int*   rank    = (int*)w;    w += align256((size_t)E * 4);
    int*   col     = (int*)w;    w += align256((size_t)E * 4);
    _Float16* w1h = (_Float16*)w; w += align256(32768 * 2);
    _Float16* w1l = (_Float16*)w; w += align256(32768 * 2);
    _Float16* w2h = (_Float16*)w; w += align256(16384 * 2);
    _Float16* w2l = (_Float16*)w; w += align256(16384 * 2);
    _Float16* w3h = (_Float16*)w; w += align256(16384 * 2);
    _Float16* w3l = (_Float16*)w; w += align256(16384 * 2);
    _Float16* w4h = (_Float16*)w; w += align256(32768 * 2);
    _Float16* w4l = (_Float16*)w; w += align256(32768 * 2);
    // arenas (aliased across phases), all fp16
    char* A1 = w;  w += align256((size_t)N * 128 * 2);   // xs | t3h+t3l
    char* A2 = w;  w += align256((size_t)N * 128 * 2);   // t1h | g2+h2s
    char* A3 = w;  w += align256((size_t)N * 128 * 2);   // t1l | gg4
    char* A4 = w;  w += align256((size_t)N * 256 * 2);   // h1h | h3h
    char* A5 = w;  w += align256((size_t)N * 256 * 2);   // h1l | h3l

    _Float16* xs  = (_Float16*)A1;
    _Float16* t1h = (_Float16*)A2;
    _Float16* t1l = (_Float16*)A3;
    _Float16* h1h = (_Float16*)A4;
    _Float16* h1l = (_Float16*)A5;
    _Float16* g2  = (_Float16*)A2;
    _Float16* h2s = (_Float16*)(A2 + (size_t)N * 64 * 2);
    _Float16* t3h = (_Float16*)A1;
    _Float16* t3l = (_Float16*)(A1 + (size_t)N * 64 * 2);
    _Float16* h3h = (_Float16*)A4;
    _Float16* h3l = (_Float16*)A5;
    _Float16* gg4 = (_Float16*)A3;

    // ---- CSR build ----
    const int nb = (N + 1023) / 1024;
    hipMemsetAsync(counts, 0, (size_t)N * 4, stream);
    count_kernel<<<(E + 255) / 256, 256, 0, stream>>>(dst, counts, rank, E);
    scan1_kernel<<<nb, 1024, 0, stream>>>(counts, row_ptr, bsum, N);
    scan2_kernel<<<1, 64, 0, stream>>>(bsum, nb);
    scan3_kernel<<<(N + 255) / 256, 256, 0, stream>>>(row_ptr, bsum, counts, dis, N);
    fill_kernel<<<(E + 255) / 256, 256, 0, stream>>>(src, dst, rank, row_ptr, col, E);

    // ---- pack weights ----
    pack_w<<<(4096 + 255) / 256, 256, 0, stream>>>(W1, w1h, w1l, 128, 256);
    pack_w<<<(2048 + 255) / 256, 256, 0, stream>>>(W2, w2h, w2l, 256, 64);
    pack_w<<<(2048 + 255) / 256, 256, 0, stream>>>(W3, w3h, w3l, 64, 256);
    pack_w<<<(4096 + 255) / 256, 256, 0, stream>>>(W4, w4h, w4l, 256, 128);

    const int gy = (N + 127) / 128;   // 391

    // ---- layer 1 (agg-first): xs = fp16(dis*x) ; t1 = Âs xs ; h1 = relu(t1 @ W1 + b1) ----
    xs_half_kernel<<<(N * 32 + 255) / 256, 256, 0, stream>>>(x, dis, xs, N * 32);
    agg4<0, 32><<<N / 8, 256, 0, stream>>>(xs, row_ptr, col, dis, nullptr,
                                           nullptr, nullptr, t1h, t1l);
    mfma_gemm<1, 128, 256><<<dim3(4, gy), 256, 0, stream>>>(t1h, t1l, w1h, w1l, dis, b1,
                                                            nullptr, h1h, h1l, N);

    // ---- layer 2 (agg-after): g2 = fp16(dis*(h1 @ W2)) ; h2s = fp16(dis*relu(agg + b2)) ----
    mfma_gemm<0, 256, 64><<<dim3(1, gy), 256, 0, stream>>>(h1h, h1l, w2h, w2l, dis, b2,
                                                           g2, nullptr, nullptr, N);
    agg4<2, 16><<<N / 16, 256, 0, stream>>>(g2, row_ptr, col, dis, b2,
                                            nullptr, h2s, nullptr, nullptr);

    // ---- layer 3 (agg-first): t3 = Âs h2s ; h3 = relu(t3 @ W3 + b3) ----
    agg4<0, 16><<<N / 16, 256, 0, stream>>>(h2s, row_ptr, col, dis, nullptr,
                                            nullptr, nullptr, t3h, t3l);
    mfma_gemm<1, 64, 256><<<dim3(4, gy), 256, 0, stream>>>(t3h, t3l, w3h, w3l, dis, b3,
                                                           nullptr, h3h, h3l, N);

    // ---- layer 4 (agg-after): gg4 = fp16(dis*(h3 @ W4)) ; out = agg + b4 ----
    mfma_gemm<0, 256, 128><<<dim3(2, gy), 256, 0, stream>>>(h3h, h3l, w4h, w4l, dis, b4,
                                                            gg4, nullptr, nullptr, N);
    agg4<3, 32><<<N / 8, 256, 0, stream>>>(gg4, row_ptr, col, dis, b4,
                                           out, nullptr, nullptr, nullptr);
}